// Round 9
// baseline (734.602 us; speedup 1.0000x reference)
//
#include <hip/hip_runtime.h>
#include <stdint.h>

// Problem constants
#define BATCH 4
#define NSEQ  2048
#define CDIM  1152
#define HB    16
#define DHD   72
#define D3    3456
#define NT    8192    // BATCH*NSEQ

typedef __attribute__((ext_vector_type(8))) short short8;       // 8 bf16 (4 VGPRs)
typedef __attribute__((ext_vector_type(8))) unsigned short u16x8;
typedef __attribute__((ext_vector_type(4))) unsigned short u16x4;
typedef __attribute__((ext_vector_type(2))) unsigned int u32x2;
typedef __attribute__((ext_vector_type(4))) float f32x4;

__device__ __forceinline__ float bf2f(unsigned short u) {
  return __uint_as_float(((unsigned)u) << 16);
}
__device__ __forceinline__ unsigned short f2bf(float f) {
  unsigned u = __float_as_uint(f);
  u += 0x7FFF + ((u >> 16) & 1);   // RNE
  return (unsigned short)(u >> 16);
}
// packed 2xf32 -> 2xbf16 (RNE) in one instruction (T12 recipe; no builtin)
__device__ __forceinline__ unsigned pkbf(float lo, float hi) {
  unsigned r;
  asm("v_cvt_pk_bf16_f32 %0, %1, %2" : "=v"(r) : "v"(lo), "v"(hi));
  return r;
}
// raw v_exp_f32: exact for |x| <= ~60 (our S is bounded by 12.3); avoids the
// ~7-instruction __ocml_exp2_f32 range-fixup expansion of exp2f.
__device__ __forceinline__ float exp2_raw(float x) {
  float r;
  asm("v_exp_f32 %0, %1" : "=v"(r) : "v"(x));
  return r;
}

// async 16B global->LDS copy: per-lane global addr, LDS dest = wave-uniform base + lane*16
__device__ __forceinline__ void gload_lds16(const unsigned short* g, unsigned short* l) {
  __builtin_amdgcn_global_load_lds(
      (const __attribute__((address_space(1))) void*)g,
      (__attribute__((address_space(3))) void*)l, 16, 0, 0);
}

// ---------------------------------------------------------------------------
// fp32 -> bf16 conversion prepass for x, w_qkv, w_proj (memory-bound).
// ---------------------------------------------------------------------------
#define XN    ((size_t)NT * CDIM)        // 9,437,184
#define WQN   ((size_t)D3 * CDIM)        // 3,981,312
#define WPN   ((size_t)CDIM * CDIM)      // 1,327,104
#define CVT_CHUNKS ((XN + WQN + WPN) / 4)  // 3,686,400 float4 chunks

__global__ __launch_bounds__(256) void cvt_bf16(
    const float* __restrict__ x, const float* __restrict__ wq,
    const float* __restrict__ wp, unsigned short* __restrict__ xb,
    unsigned short* __restrict__ wqb, unsigned short* __restrict__ wpb) {
  size_t c = (size_t)blockIdx.x * 256 + threadIdx.x;
  if (c >= CVT_CHUNKS) return;
  const float* src;
  unsigned short* dst;
  size_t e = c * 4;
  if (e < XN) { src = x + e; dst = xb + e; }
  else if (e < XN + WQN) { src = wq + (e - XN); dst = wqb + (e - XN); }
  else { src = wp + (e - XN - WQN); dst = wpb + (e - XN - WQN); }
  f32x4 v = *(const f32x4*)src;
  u16x4 r;
#pragma unroll
  for (int i = 0; i < 4; i++) r[i] = f2bf(v[i]);
  *(u16x4*)dst = r;
}

// ---------------------------------------------------------------------------
// GEMM-256: qkv = x * Wqkv^T, bf16 in, fp32 acc, bf16 scatter out.
// [UNCHANGED from R8]
// ---------------------------------------------------------------------------
__global__ __launch_bounds__(512, 2) void gemm256_qkv(
    const unsigned short* __restrict__ A, const unsigned short* __restrict__ Bt,
    unsigned short* __restrict__ qkvb, unsigned short* __restrict__ Vt) {
  __shared__ __attribute__((aligned(16))) unsigned short sA[2 * 256 * 64];  // 64 KB
  __shared__ __attribute__((aligned(16))) unsigned short sB[2 * 256 * 64];  // 64 KB

  const int K = CDIM;
  const int tid  = threadIdx.x;
  const int lane = tid & 63;
  const int w    = tid >> 6;          // 0..7
  const int wm   = w >> 2, wn = w & 3;
  const int quad = lane >> 4, l16 = lane & 15;
  const int s7l  = l16 & 7;

  const int lb  = blockIdx.y * gridDim.x + blockIdx.x;   // gridDim.x = 14
  const int xcd = lb & 7;
  const int pos = lb >> 3;            // 0..55
  const int m0 = (xcd * 4 + (pos & 3)) * 256;
  const int n0 = (pos >> 2) * 256;    // 0..13 tiles (tile 13 partial)

  const int r8 = lane >> 3;
  const int cu = (lane & 7) ^ r8;
  const unsigned short* gA = A  + (size_t)(m0 + w * 8 + r8) * K + cu * 8;
  const unsigned short* gB = Bt + (size_t)(n0 + w * 8 + r8) * K + cu * 8;

  const f32x4 zero = {0.f, 0.f, 0.f, 0.f};
  f32x4 acc[8][4];
#pragma unroll
  for (int i = 0; i < 8; i++)
#pragma unroll
    for (int j = 0; j < 4; j++) acc[i][j] = zero;

#pragma unroll
  for (int g = 0; g < 4; g++) {
    gload_lds16(gA + (size_t)g * 64 * K, sA + g * 4096 + w * 512);
    gload_lds16(gB + (size_t)g * 64 * K, sB + g * 4096 + w * 512);
  }
  __syncthreads();

  for (int t = 0; t < 18; t++) {
    const unsigned short* A_ = sA + (t & 1) * 16384;
    const unsigned short* B_ = sB + (t & 1) * 16384;
    unsigned short* An = sA + ((t + 1) & 1) * 16384;
    unsigned short* Bn = sB + ((t + 1) & 1) * 16384;
    const int ktn = (t + 1) * 64;

#pragma unroll
    for (int kk = 0; kk < 2; kk++) {
      short8 a[8], b[4];
#pragma unroll
      for (int i = 0; i < 8; i++)
        a[i] = *(const short8*)(A_ + (wm * 128 + i * 16 + l16) * 64 +
                                (((kk * 4 + quad) ^ s7l) << 3));
#pragma unroll
      for (int j = 0; j < 4; j++)
        b[j] = *(const short8*)(B_ + (wn * 64 + j * 16 + l16) * 64 +
                                (((kk * 4 + quad) ^ s7l) << 3));

      if (t < 17) {
#pragma unroll
        for (int g = 0; g < 4; g++) {
          if (kk == 0)
            gload_lds16(gA + (size_t)g * 64 * K + ktn, An + g * 4096 + w * 512);
          else
            gload_lds16(gB + (size_t)g * 64 * K + ktn, Bn + g * 4096 + w * 512);
        }
      }

      __builtin_amdgcn_s_setprio(1);
#pragma unroll
      for (int i = 0; i < 8; i++)
#pragma unroll
        for (int j = 0; j < 4; j++)
          acc[i][j] = __builtin_amdgcn_mfma_f32_16x16x32_bf16(a[i], b[j], acc[i][j], 0, 0, 0);
      __builtin_amdgcn_s_setprio(0);
    }
    __syncthreads();
  }

#pragma unroll
  for (int i = 0; i < 8; i++) {
    int row = m0 + wm * 128 + i * 16 + quad * 4;
    int b_ = row >> 11;
    int n  = row & 2047;
#pragma unroll
    for (int j = 0; j < 4; j++) {
      int col = n0 + wn * 64 + j * 16 + l16;
      if (col < D3) {
        int s  = col / CDIM;
        int rm = col - s * CDIM;
        int h  = rm / DHD;
        int dh = rm - h * DHD;
        if (s == 2) {
#pragma unroll
          for (int r = 0; r < 4; r++)
            Vt[((size_t)(b_ * HB + h) * DHD + dh) * NSEQ + n + r] = f2bf(acc[i][j][r]);
        } else {
#pragma unroll
          for (int r = 0; r < 4; r++)
            qkvb[(((size_t)(s * BATCH + b_) * HB + h) * NSEQ + (n + r)) * DHD + dh] =
                f2bf(acc[i][j][r]);
        }
      }
    }
  }
}

// ---------------------------------------------------------------------------
// GEMM-BT (bf16 in): output projection. [UNCHANGED from R8]
// ---------------------------------------------------------------------------
__global__ __launch_bounds__(256) void gemm_bt(
    const unsigned short* __restrict__ A, const unsigned short* __restrict__ Bt,
    const float* __restrict__ bias, float* __restrict__ Cout, int M, int Dn, int K) {
  __shared__ __attribute__((aligned(16))) unsigned short sA[128 * 64];  // 16 KB
  __shared__ __attribute__((aligned(16))) unsigned short sB[128 * 64];  // 16 KB

  const int tid  = threadIdx.x;
  const int lane = tid & 63;
  const int w    = tid >> 6;
  const int wm   = w >> 1, wn = w & 1;
  const int quad = lane >> 4, l16 = lane & 15;
  const int s7l  = l16 & 7;

  const int gx  = gridDim.x;
  const int lb  = blockIdx.y * gx + blockIdx.x;
  const int xcd = lb & 7;
  const int pos = lb >> 3;
  const int m0 = ((xcd << 3) + (pos & 7)) * 128;
  const int n0 = (pos >> 3) * 128;

  const int r8 = lane >> 3;
  const int cu = (lane & 7) ^ r8;
  const unsigned short* gA = A  + (size_t)(m0 + w * 32 + r8) * K + cu * 8;
  const unsigned short* gB = Bt + (size_t)(n0 + w * 32 + r8) * K + cu * 8;

  const f32x4 zero = {0.f, 0.f, 0.f, 0.f};
  f32x4 acc[4][4];
#pragma unroll
  for (int i = 0; i < 4; i++)
#pragma unroll
    for (int j = 0; j < 4; j++) acc[i][j] = zero;

  for (int kt = 0; kt < K; kt += 64) {
#pragma unroll
    for (int i = 0; i < 4; i++) {
      gload_lds16(gA + (size_t)i * 8 * K + kt, sA + (w * 4 + i) * 512);
      gload_lds16(gB + (size_t)i * 8 * K + kt, sB + (w * 4 + i) * 512);
    }
    __syncthreads();

#pragma unroll
    for (int kk = 0; kk < 2; kk++) {
      short8 a[4], b[4];
#pragma unroll
      for (int i = 0; i < 4; i++) {
        a[i] = *(const short8*)(sA + (wm * 64 + i * 16 + l16) * 64 +
                                (((kk * 4 + quad) ^ s7l) << 3));
        b[i] = *(const short8*)(sB + (wn * 64 + i * 16 + l16) * 64 +
                                (((kk * 4 + quad) ^ s7l) << 3));
      }
#pragma unroll
      for (int i = 0; i < 4; i++)
#pragma unroll
        for (int j = 0; j < 4; j++)
          acc[i][j] = __builtin_amdgcn_mfma_f32_16x16x32_bf16(a[i], b[j], acc[i][j], 0, 0, 0);
    }
    __syncthreads();
  }

#pragma unroll
  for (int i = 0; i < 4; i++) {
    int row = m0 + wm * 64 + i * 16 + quad * 4;
#pragma unroll
    for (int j = 0; j < 4; j++) {
      int col = n0 + wn * 64 + j * 16 + l16;
      float bb = bias ? bias[col] : 0.f;
#pragma unroll
      for (int r = 0; r < 4; r++)
        Cout[(size_t)(row + r) * Dn + col] = acc[i][j][r] + bb;
    }
  }
}

// ---------------------------------------------------------------------------
// RoPE + RMSNorm. [UNCHANGED from R8]
// ---------------------------------------------------------------------------
__global__ __launch_bounds__(256) void rope_rms(
    unsigned short* __restrict__ qkvb,
    const float* __restrict__ qw, const float* __restrict__ kw) {
  const int blk = blockIdx.x;
  const int b = blk >> 11;
  const int n = blk & 2047;
  const int tid = threadIdx.x;

  __shared__ float sv[2][CDIM];   // 9216 B
  __shared__ float srsq[2][HB];

  const float nf = (float)n;
  const float l2t_over_half = 13.287712379549449f / 36.0f;  // log2(10000)/36
  const float scale2 = 0.17002329230297715f;                // 72^-0.5 * log2(e)

  for (int g = tid; g < 288; g += 256) {
    int sel = (g >= 144) ? 1 : 0;
    int gg  = g - sel * 144;
    int h   = gg / 9;
    int u   = gg - h * 9;
    const unsigned short* src =
        qkvb + (((size_t)(sel * BATCH + b) * HB + h) * NSEQ + n) * DHD + u * 8;
    u16x8 v = *(const u16x8*)src;
    float* dst = &sv[sel][h * DHD + u * 8];
#pragma unroll
    for (int r = 0; r < 8; r++) dst[r] = bf2f(v[r]);
  }
  __syncthreads();

  for (int p = tid; p < 1152; p += 256) {
    int sel = (p >= 576) ? 1 : 0;
    int pp  = p - sel * 576;
    int h   = pp / 36;
    int i   = pp - h * 36;
    float* row = &sv[sel][h * DHD];
    float x1 = row[i], x2 = row[i + 36];
    float ang = nf * exp2f(-l2t_over_half * (float)i);
    float sn, cs;
    __sincosf(ang, &sn, &cs);
    row[i]      = x1 * cs - x2 * sn;
    row[i + 36] = x2 * cs + x1 * sn;
  }
  __syncthreads();

  if (tid < 128) {
    int sel = tid >> 6;
    int h = (tid & 63) >> 2, p = tid & 3;
    float s = 0.f;
#pragma unroll
    for (int d = 0; d < 18; d++) {
      float v = sv[sel][h * DHD + p * 18 + d];
      s += v * v;
    }
    s += __shfl_xor(s, 1);
    s += __shfl_xor(s, 2);
    if (p == 0)
      srsq[sel][h] = rsqrtf(s * (1.0f / 72.0f) + 1e-6f) * (sel ? 1.0f : scale2);
  }
  __syncthreads();

  for (int g = tid; g < 288; g += 256) {
    int sel = (g >= 144) ? 1 : 0;
    int gg  = g - sel * 144;
    int h   = gg / 9;
    int u   = gg - h * 9;
    float rs = srsq[sel][h];
    const float* wn = (sel ? kw : qw) + u * 8;
    const float* s = &sv[sel][h * DHD + u * 8];
    u16x8 o;
#pragma unroll
    for (int r = 0; r < 8; r++) o[r] = f2bf(s[r] * rs * wn[r]);
    unsigned short* dst =
        qkvb + (((size_t)(sel * BATCH + b) * HB + h) * NSEQ + n) * DHD + u * 8;
    *(u16x8*)dst = o;
  }
}

// ---------------------------------------------------------------------------
// Flash attention, no-max softmax. QBLK=256: 512 thr = 8 waves, each owning
// 32 q-rows (2 fused q-tiles of 16 -- per-wave structure unchanged from R5).
// Halves K/V global re-reads (8 blocks/head vs 16) and barrier/staging
// events per unit work. KV tiles of 64. S^T via swapped mfma(K,Q); raw
// v_exp_f32 (exp2_raw) + cvt_pk pack -> b64 writes into XOR-swizzled sP.
// LDS 52224 B -> 3 blocks/CU (24 waves, 6/SIMD). Schedule per tile
// (2 barriers): S+pack | F | issue K(t+1) | PV | E | issue V(t+1).
// ---------------------------------------------------------------------------
__global__ __launch_bounds__(512, 6) void flash_attn(
    const unsigned short* __restrict__ qkvb, const unsigned short* __restrict__ Vt,
    unsigned short* __restrict__ AO) {
  __shared__ __attribute__((aligned(16))) unsigned short sK[64 * 72];    //  9216 B
  __shared__ __attribute__((aligned(16))) unsigned short sVt[80 * 64];   // 10240 B
  __shared__ __attribute__((aligned(16))) unsigned short sP[256 * 64];   // 32768 B

  const int tid  = threadIdx.x;
  const int w    = tid >> 6;          // 0..7
  const int lane = tid & 63;
  const int quad = lane >> 4, l16 = lane & 15;
  const int s7   = l16 & 7;
  const int q0 = blockIdx.x * 256;
  const int h = blockIdx.y, b = blockIdx.z;

  const unsigned short* Qb = qkvb + ((size_t)(0 * BATCH + b) * HB + h) * NSEQ * DHD;
  const unsigned short* Kb = qkvb + ((size_t)(1 * BATCH + b) * HB + h) * NSEQ * DHD;
  const unsigned short* Vb = Vt + (size_t)(b * HB + h) * DHD * NSEQ;

  const short8 zs = {0, 0, 0, 0, 0, 0, 0, 0};
  const f32x4 zero = {0.f, 0.f, 0.f, 0.f};

  // staging source pointers; issue i = w + 8*j (9 x 1KB per array; wave 0
  // issues i=0 and i=8, waves 1..7 issue i=w).
  const int vswz = ((lane & 7) ^ (lane >> 3)) * 8;
  const unsigned short* pKn[2];
  const unsigned short* pVn[2];
#pragma unroll
  for (int j = 0; j < 2; j++) {
    int i = w + 8 * j;
    int ii = (i < 9) ? i : 0;
    pKn[j] = Kb + ii * 512 + lane * 8;
    pVn[j] = Vb + (size_t)(ii * 8 + (lane >> 3)) * NSEQ + vswz;
  }

  // prologue: issue K(0) -> sK and V(0) -> sVt
#pragma unroll
  for (int j = 0; j < 2; j++) {
    int i = w + 8 * j;
    if (i < 9) {
      gload_lds16(pKn[j], sK + i * 512);
      gload_lds16(pVn[j], sVt + i * 512);
      pKn[j] += 64 * 72;
      pVn[j] += 64;
    }
  }

  // ones row (d=72) and zero rows (73..79) of V; staging never touches them
  {
    int e = tid;   // 512 threads cover 512 entries exactly
    sVt[72 * 64 + e] = (e < 64) ? (unsigned short)0x3F80 : (unsigned short)0;
  }

  // Q fragments: 2 q-tiles per wave, rows q0 + w*32 + qt*16 + l16
  short8 aq[2][3];
#pragma unroll
  for (int qt = 0; qt < 2; qt++) {
    const unsigned short* qrow = Qb + (size_t)(q0 + w * 32 + qt * 16 + l16) * DHD;
    aq[qt][0] = *(const short8*)(qrow + quad * 8);
    aq[qt][1] = *(const short8*)(qrow + 32 + quad * 8);
    aq[qt][2] = (quad == 0) ? *(const short8*)(qrow + 64) : zs;
  }

  f32x4 o[2][5];
#pragma unroll
  for (int qt = 0; qt < 2; qt++)
#pragma unroll
    for (int nb = 0; nb < 5; nb++) o[qt][nb] = zero;

  // S-phase + pack (both q-tiles; each K fragment read once). SWAPPED
  // operands: D = S^T (row=kv, col=q); lane packs 4 consecutive kv with
  // 2 cvt_pk -> one b64 write into swizzled sP rows qt*128 + w*16 + l16.
  auto sphase_pack = [&]() {
    f32x4 st[2][4];
    __builtin_amdgcn_s_setprio(1);
#pragma unroll
    for (int nk = 0; nk < 4; nk++) {
      const unsigned short* kr = sK + (nk * 16 + l16) * 72;
      short8 kf0 = *(const short8*)(kr + quad * 8);
      short8 kf1 = *(const short8*)(kr + 32 + quad * 8);
      short8 kf2 = *(const short8*)(kr + 64);  // uniform; bogus k-slots masked by aq[2]=0
      f32x4 s0 = zero, s1 = zero;
      s0 = __builtin_amdgcn_mfma_f32_16x16x32_bf16(kf0, aq[0][0], s0, 0, 0, 0);
      s1 = __builtin_amdgcn_mfma_f32_16x16x32_bf16(kf0, aq[1][0], s1, 0, 0, 0);
      s0 = __builtin_amdgcn_mfma_f32_16x16x32_bf16(kf1, aq[0][1], s0, 0, 0, 0);
      s1 = __builtin_amdgcn_mfma_f32_16x16x32_bf16(kf1, aq[1][1], s1, 0, 0, 0);
      s0 = __builtin_amdgcn_mfma_f32_16x16x32_bf16(kf2, aq[0][2], s0, 0, 0, 0);
      s1 = __builtin_amdgcn_mfma_f32_16x16x32_bf16(kf2, aq[1][2], s1, 0, 0, 0);
      st[0][nk] = s0;
      st[1][nk] = s1;
    }
    __builtin_amdgcn_s_setprio(0);
#pragma unroll
    for (int qt = 0; qt < 2; qt++) {
      unsigned short* prow = sP + (qt * 128 + w * 16 + l16) * 64 + (quad & 1) * 4;
#pragma unroll
      for (int nk = 0; nk < 4; nk++) {
        int uoff = ((nk * 2 + (quad >> 1)) ^ s7) << 3;
        u32x2 pr;
        pr[0] = pkbf(exp2_raw(st[qt][nk][0]), exp2_raw(st[qt][nk][1]));
        pr[1] = pkbf(exp2_raw(st[qt][nk][2]), exp2_raw(st[qt][nk][3]));
        *(u32x2*)(prow + uoff) = pr;
      }
    }
  };

  // PV for the current tile: each V fragment read once, feeds both q-tiles.
  auto pv_phase = [&]() {
    __builtin_amdgcn_s_setprio(1);
#pragma unroll
    for (int kb = 0; kb < 2; kb++) {
      const unsigned short* pp =
          sP + (w * 16 + l16) * 64 + (((kb * 4 + quad) ^ s7) << 3);
      short8 pf0 = *(const short8*)pp;
      short8 pf1 = *(const short8*)(pp + 128 * 64);  // qt=1 rows (+128: same row&7)
#pragma unroll
      for (int nb = 0; nb < 5; nb++) {
        short8 vf = *(const short8*)(sVt + (nb * 16 + l16) * 64 +
                                     (((kb * 4 + quad) ^ s7) << 3));
        o[0][nb] = __builtin_amdgcn_mfma_f32_16x16x32_bf16(pf0, vf, o[0][nb], 0, 0, 0);
        o[1][nb] = __builtin_amdgcn_mfma_f32_16x16x32_bf16(pf1, vf, o[1][nb], 0, 0, 0);
      }
    }
    __builtin_amdgcn_s_setprio(0);
  };

  __syncthreads();   // drain K(0), V(0)

  for (int t = 0; t < 32; t++) {
    sphase_pack();           // S(t)+pack(t): reads sK, writes own sP rows

    __syncthreads();         // F: sK readers done; V(t) DMA drained (prev E)

    if (t < 31) {            // issue K(t+1) into sK (readers finished)
#pragma unroll
      for (int j = 0; j < 2; j++) {
        int i = w + 8 * j;
        if (i < 9) { gload_lds16(pKn[j], sK + i * 512); pKn[j] += 64 * 72; }
      }
    }

    pv_phase();              // PV(t): reads sVt=V(t), sP=P(t)

    __syncthreads();         // E: sVt readers done; K(t+1) DMA drained

    if (t < 31) {            // issue V(t+1); drains at next F
#pragma unroll
      for (int j = 0; j < 2; j++) {
        int i = w + 8 * j;
        if (i < 9) { gload_lds16(pVn[j], sVt + i * 512); pVn[j] += 64; }
      }
    }
  }

  // epilogue: l sits at dh=72 (nb=4, l16=8); broadcast within quad, normalize
#pragma unroll
  for (int qt = 0; qt < 2; qt++) {
    float inv[4];
#pragma unroll
    for (int r = 0; r < 4; r++)
      inv[r] = 1.0f / __shfl(o[qt][4][r], (quad << 4) + 8, 64);
    const int qrow = q0 + w * 32 + qt * 16 + quad * 4;
#pragma unroll
    for (int nb = 0; nb < 5; nb++) {
      int dh = nb * 16 + l16;
      if (dh < DHD) {
#pragma unroll
        for (int r = 0; r < 4; r++)
          AO[((size_t)b * NSEQ + qrow + r) * CDIM + h * DHD + dh] =
              f2bf(o[qt][nb][r] * inv[r]);
      }
    }
  }
}

// ---------------------------------------------------------------------------
extern "C" void kernel_launch(void* const* d_in, const int* in_sizes, int n_in,
                              void* d_out, int out_size, void* d_ws, size_t ws_size,
                              hipStream_t stream) {
  const float* x      = (const float*)d_in[0];
  const float* w_qkv  = (const float*)d_in[1];
  const float* w_proj = (const float*)d_in[2];
  const float* b_proj = (const float*)d_in[3];
  const float* qnw    = (const float*)d_in[4];
  const float* knw    = (const float*)d_in[5];
  float* out = (float*)d_out;

  char* ws = (char*)d_ws;
  // layout (bytes): xb 18.9M | wqkvb 8.0M | wprojb 2.7M | qkvb 37.7M | Vt 18.9M
  // AO aliases xb (xb dead after gemm1). Total 86.1 MB.
  unsigned short* xb    = (unsigned short*)(ws);
  unsigned short* wqkvb = (unsigned short*)(ws + 18874368);
  unsigned short* wprojb= (unsigned short*)(ws + 26836992);
  unsigned short* qkvb  = (unsigned short*)(ws + 29491200);
  unsigned short* Vt    = (unsigned short*)(ws + 67239936);
  unsigned short* AO    = xb;

  cvt_bf16<<<dim3((CVT_CHUNKS + 255) / 256), 256, 0, stream>>>(
      x, w_qkv, w_proj, xb, wqkvb, wprojb);
  gemm256_qkv<<<dim3(14, 32), 512, 0, stream>>>(xb, wqkvb, qkvb, Vt);
  rope_rms<<<dim3(NT), 256, 0, stream>>>(qkvb, qnw, knw);
  flash_attn<<<dim3(NSEQ / 256, HB, BATCH), 512, 0, stream>>>(qkvb, Vt, AO);
  gemm_bt<<<dim3(CDIM / 128, NT / 128), 256, 0, stream>>>(
      AO, wprojb, b_proj, out, NT, CDIM, CDIM);
}

// Round 10
// 323.192 us; speedup vs baseline: 2.2730x; 2.2730x over previous
//
#include <hip/hip_runtime.h>
#include <stdint.h>

// Problem constants
#define BATCH 4
#define NSEQ  2048
#define CDIM  1152
#define HB    16
#define DHD   72
#define D3    3456
#define NT    8192    // BATCH*NSEQ

typedef __attribute__((ext_vector_type(8))) short short8;       // 8 bf16 (4 VGPRs)
typedef __attribute__((ext_vector_type(8))) unsigned short u16x8;
typedef __attribute__((ext_vector_type(4))) unsigned short u16x4;
typedef __attribute__((ext_vector_type(2))) unsigned int u32x2;
typedef __attribute__((ext_vector_type(4))) float f32x4;

__device__ __forceinline__ float bf2f(unsigned short u) {
  return __uint_as_float(((unsigned)u) << 16);
}
__device__ __forceinline__ unsigned short f2bf(float f) {
  unsigned u = __float_as_uint(f);
  u += 0x7FFF + ((u >> 16) & 1);   // RNE
  return (unsigned short)(u >> 16);
}
// packed 2xf32 -> 2xbf16 (RNE) in one instruction (T12 recipe; no builtin)
__device__ __forceinline__ unsigned pkbf(float lo, float hi) {
  unsigned r;
  asm("v_cvt_pk_bf16_f32 %0, %1, %2" : "=v"(r) : "v"(lo), "v"(hi));
  return r;
}
// raw v_exp_f32: exact for |x| <= ~60 (our S is bounded by 12.3); avoids the
// ~7-instruction __ocml_exp2_f32 range-fixup expansion of exp2f.
__device__ __forceinline__ float exp2_raw(float x) {
  float r;
  asm("v_exp_f32 %0, %1" : "=v"(r) : "v"(x));
  return r;
}

// async 16B global->LDS copy: per-lane global addr, LDS dest = wave-uniform base + lane*16
__device__ __forceinline__ void gload_lds16(const unsigned short* g, unsigned short* l) {
  __builtin_amdgcn_global_load_lds(
      (const __attribute__((address_space(1))) void*)g,
      (__attribute__((address_space(3))) void*)l, 16, 0, 0);
}

// ---------------------------------------------------------------------------
// fp32 -> bf16 conversion prepass for x, w_qkv, w_proj (memory-bound).
// ---------------------------------------------------------------------------
#define XN    ((size_t)NT * CDIM)        // 9,437,184
#define WQN   ((size_t)D3 * CDIM)        // 3,981,312
#define WPN   ((size_t)CDIM * CDIM)      // 1,327,104
#define CVT_CHUNKS ((XN + WQN + WPN) / 4)  // 3,686,400 float4 chunks

__global__ __launch_bounds__(256) void cvt_bf16(
    const float* __restrict__ x, const float* __restrict__ wq,
    const float* __restrict__ wp, unsigned short* __restrict__ xb,
    unsigned short* __restrict__ wqb, unsigned short* __restrict__ wpb) {
  size_t c = (size_t)blockIdx.x * 256 + threadIdx.x;
  if (c >= CVT_CHUNKS) return;
  const float* src;
  unsigned short* dst;
  size_t e = c * 4;
  if (e < XN) { src = x + e; dst = xb + e; }
  else if (e < XN + WQN) { src = wq + (e - XN); dst = wqb + (e - XN); }
  else { src = wp + (e - XN - WQN); dst = wpb + (e - XN - WQN); }
  f32x4 v = *(const f32x4*)src;
  u16x4 r;
#pragma unroll
  for (int i = 0; i < 4; i++) r[i] = f2bf(v[i]);
  *(u16x4*)dst = r;
}

// ---------------------------------------------------------------------------
// GEMM-256: qkv = x * Wqkv^T, bf16 in, fp32 acc, bf16 scatter out.
// [UNCHANGED from R8]
// ---------------------------------------------------------------------------
__global__ __launch_bounds__(512, 2) void gemm256_qkv(
    const unsigned short* __restrict__ A, const unsigned short* __restrict__ Bt,
    unsigned short* __restrict__ qkvb, unsigned short* __restrict__ Vt) {
  __shared__ __attribute__((aligned(16))) unsigned short sA[2 * 256 * 64];  // 64 KB
  __shared__ __attribute__((aligned(16))) unsigned short sB[2 * 256 * 64];  // 64 KB

  const int K = CDIM;
  const int tid  = threadIdx.x;
  const int lane = tid & 63;
  const int w    = tid >> 6;          // 0..7
  const int wm   = w >> 2, wn = w & 3;
  const int quad = lane >> 4, l16 = lane & 15;
  const int s7l  = l16 & 7;

  const int lb  = blockIdx.y * gridDim.x + blockIdx.x;   // gridDim.x = 14
  const int xcd = lb & 7;
  const int pos = lb >> 3;            // 0..55
  const int m0 = (xcd * 4 + (pos & 3)) * 256;
  const int n0 = (pos >> 2) * 256;    // 0..13 tiles (tile 13 partial)

  const int r8 = lane >> 3;
  const int cu = (lane & 7) ^ r8;
  const unsigned short* gA = A  + (size_t)(m0 + w * 8 + r8) * K + cu * 8;
  const unsigned short* gB = Bt + (size_t)(n0 + w * 8 + r8) * K + cu * 8;

  const f32x4 zero = {0.f, 0.f, 0.f, 0.f};
  f32x4 acc[8][4];
#pragma unroll
  for (int i = 0; i < 8; i++)
#pragma unroll
    for (int j = 0; j < 4; j++) acc[i][j] = zero;

#pragma unroll
  for (int g = 0; g < 4; g++) {
    gload_lds16(gA + (size_t)g * 64 * K, sA + g * 4096 + w * 512);
    gload_lds16(gB + (size_t)g * 64 * K, sB + g * 4096 + w * 512);
  }
  __syncthreads();

  for (int t = 0; t < 18; t++) {
    const unsigned short* A_ = sA + (t & 1) * 16384;
    const unsigned short* B_ = sB + (t & 1) * 16384;
    unsigned short* An = sA + ((t + 1) & 1) * 16384;
    unsigned short* Bn = sB + ((t + 1) & 1) * 16384;
    const int ktn = (t + 1) * 64;

#pragma unroll
    for (int kk = 0; kk < 2; kk++) {
      short8 a[8], b[4];
#pragma unroll
      for (int i = 0; i < 8; i++)
        a[i] = *(const short8*)(A_ + (wm * 128 + i * 16 + l16) * 64 +
                                (((kk * 4 + quad) ^ s7l) << 3));
#pragma unroll
      for (int j = 0; j < 4; j++)
        b[j] = *(const short8*)(B_ + (wn * 64 + j * 16 + l16) * 64 +
                                (((kk * 4 + quad) ^ s7l) << 3));

      if (t < 17) {
#pragma unroll
        for (int g = 0; g < 4; g++) {
          if (kk == 0)
            gload_lds16(gA + (size_t)g * 64 * K + ktn, An + g * 4096 + w * 512);
          else
            gload_lds16(gB + (size_t)g * 64 * K + ktn, Bn + g * 4096 + w * 512);
        }
      }

      __builtin_amdgcn_s_setprio(1);
#pragma unroll
      for (int i = 0; i < 8; i++)
#pragma unroll
        for (int j = 0; j < 4; j++)
          acc[i][j] = __builtin_amdgcn_mfma_f32_16x16x32_bf16(a[i], b[j], acc[i][j], 0, 0, 0);
      __builtin_amdgcn_s_setprio(0);
    }
    __syncthreads();
  }

#pragma unroll
  for (int i = 0; i < 8; i++) {
    int row = m0 + wm * 128 + i * 16 + quad * 4;
    int b_ = row >> 11;
    int n  = row & 2047;
#pragma unroll
    for (int j = 0; j < 4; j++) {
      int col = n0 + wn * 64 + j * 16 + l16;
      if (col < D3) {
        int s  = col / CDIM;
        int rm = col - s * CDIM;
        int h  = rm / DHD;
        int dh = rm - h * DHD;
        if (s == 2) {
#pragma unroll
          for (int r = 0; r < 4; r++)
            Vt[((size_t)(b_ * HB + h) * DHD + dh) * NSEQ + n + r] = f2bf(acc[i][j][r]);
        } else {
#pragma unroll
          for (int r = 0; r < 4; r++)
            qkvb[(((size_t)(s * BATCH + b_) * HB + h) * NSEQ + (n + r)) * DHD + dh] =
                f2bf(acc[i][j][r]);
        }
      }
    }
  }
}

// ---------------------------------------------------------------------------
// GEMM-BT (bf16 in): output projection. [UNCHANGED from R8]
// ---------------------------------------------------------------------------
__global__ __launch_bounds__(256) void gemm_bt(
    const unsigned short* __restrict__ A, const unsigned short* __restrict__ Bt,
    const float* __restrict__ bias, float* __restrict__ Cout, int M, int Dn, int K) {
  __shared__ __attribute__((aligned(16))) unsigned short sA[128 * 64];  // 16 KB
  __shared__ __attribute__((aligned(16))) unsigned short sB[128 * 64];  // 16 KB

  const int tid  = threadIdx.x;
  const int lane = tid & 63;
  const int w    = tid >> 6;
  const int wm   = w >> 1, wn = w & 1;
  const int quad = lane >> 4, l16 = lane & 15;
  const int s7l  = l16 & 7;

  const int gx  = gridDim.x;
  const int lb  = blockIdx.y * gx + blockIdx.x;
  const int xcd = lb & 7;
  const int pos = lb >> 3;
  const int m0 = ((xcd << 3) + (pos & 7)) * 128;
  const int n0 = (pos >> 3) * 128;

  const int r8 = lane >> 3;
  const int cu = (lane & 7) ^ r8;
  const unsigned short* gA = A  + (size_t)(m0 + w * 32 + r8) * K + cu * 8;
  const unsigned short* gB = Bt + (size_t)(n0 + w * 32 + r8) * K + cu * 8;

  const f32x4 zero = {0.f, 0.f, 0.f, 0.f};
  f32x4 acc[4][4];
#pragma unroll
  for (int i = 0; i < 4; i++)
#pragma unroll
    for (int j = 0; j < 4; j++) acc[i][j] = zero;

  for (int kt = 0; kt < K; kt += 64) {
#pragma unroll
    for (int i = 0; i < 4; i++) {
      gload_lds16(gA + (size_t)i * 8 * K + kt, sA + (w * 4 + i) * 512);
      gload_lds16(gB + (size_t)i * 8 * K + kt, sB + (w * 4 + i) * 512);
    }
    __syncthreads();

#pragma unroll
    for (int kk = 0; kk < 2; kk++) {
      short8 a[4], b[4];
#pragma unroll
      for (int i = 0; i < 4; i++) {
        a[i] = *(const short8*)(sA + (wm * 64 + i * 16 + l16) * 64 +
                                (((kk * 4 + quad) ^ s7l) << 3));
        b[i] = *(const short8*)(sB + (wn * 64 + i * 16 + l16) * 64 +
                                (((kk * 4 + quad) ^ s7l) << 3));
      }
#pragma unroll
      for (int i = 0; i < 4; i++)
#pragma unroll
        for (int j = 0; j < 4; j++)
          acc[i][j] = __builtin_amdgcn_mfma_f32_16x16x32_bf16(a[i], b[j], acc[i][j], 0, 0, 0);
    }
    __syncthreads();
  }

#pragma unroll
  for (int i = 0; i < 4; i++) {
    int row = m0 + wm * 64 + i * 16 + quad * 4;
#pragma unroll
    for (int j = 0; j < 4; j++) {
      int col = n0 + wn * 64 + j * 16 + l16;
      float bb = bias ? bias[col] : 0.f;
#pragma unroll
      for (int r = 0; r < 4; r++)
        Cout[(size_t)(row + r) * Dn + col] = acc[i][j][r] + bb;
    }
  }
}

// ---------------------------------------------------------------------------
// RoPE + RMSNorm. [UNCHANGED from R8]
// ---------------------------------------------------------------------------
__global__ __launch_bounds__(256) void rope_rms(
    unsigned short* __restrict__ qkvb,
    const float* __restrict__ qw, const float* __restrict__ kw) {
  const int blk = blockIdx.x;
  const int b = blk >> 11;
  const int n = blk & 2047;
  const int tid = threadIdx.x;

  __shared__ float sv[2][CDIM];   // 9216 B
  __shared__ float srsq[2][HB];

  const float nf = (float)n;
  const float l2t_over_half = 13.287712379549449f / 36.0f;  // log2(10000)/36
  const float scale2 = 0.17002329230297715f;                // 72^-0.5 * log2(e)

  for (int g = tid; g < 288; g += 256) {
    int sel = (g >= 144) ? 1 : 0;
    int gg  = g - sel * 144;
    int h   = gg / 9;
    int u   = gg - h * 9;
    const unsigned short* src =
        qkvb + (((size_t)(sel * BATCH + b) * HB + h) * NSEQ + n) * DHD + u * 8;
    u16x8 v = *(const u16x8*)src;
    float* dst = &sv[sel][h * DHD + u * 8];
#pragma unroll
    for (int r = 0; r < 8; r++) dst[r] = bf2f(v[r]);
  }
  __syncthreads();

  for (int p = tid; p < 1152; p += 256) {
    int sel = (p >= 576) ? 1 : 0;
    int pp  = p - sel * 576;
    int h   = pp / 36;
    int i   = pp - h * 36;
    float* row = &sv[sel][h * DHD];
    float x1 = row[i], x2 = row[i + 36];
    float ang = nf * exp2f(-l2t_over_half * (float)i);
    float sn, cs;
    __sincosf(ang, &sn, &cs);
    row[i]      = x1 * cs - x2 * sn;
    row[i + 36] = x2 * cs + x1 * sn;
  }
  __syncthreads();

  if (tid < 128) {
    int sel = tid >> 6;
    int h = (tid & 63) >> 2, p = tid & 3;
    float s = 0.f;
#pragma unroll
    for (int d = 0; d < 18; d++) {
      float v = sv[sel][h * DHD + p * 18 + d];
      s += v * v;
    }
    s += __shfl_xor(s, 1);
    s += __shfl_xor(s, 2);
    if (p == 0)
      srsq[sel][h] = rsqrtf(s * (1.0f / 72.0f) + 1e-6f) * (sel ? 1.0f : scale2);
  }
  __syncthreads();

  for (int g = tid; g < 288; g += 256) {
    int sel = (g >= 144) ? 1 : 0;
    int gg  = g - sel * 144;
    int h   = gg / 9;
    int u   = gg - h * 9;
    float rs = srsq[sel][h];
    const float* wn = (sel ? kw : qw) + u * 8;
    const float* s = &sv[sel][h * DHD + u * 8];
    u16x8 o;
#pragma unroll
    for (int r = 0; r < 8; r++) o[r] = f2bf(s[r] * rs * wn[r]);
    unsigned short* dst =
        qkvb + (((size_t)(sel * BATCH + b) * HB + h) * NSEQ + n) * DHD + u * 8;
    *(u16x8*)dst = o;
  }
}

// ---------------------------------------------------------------------------
// Flash attention, no-max softmax. QBLK=256: 512 thr = 8 waves, each owning
// 32 q-rows (2 fused q-tiles of 16). KV tiles of 64. S^T via swapped
// mfma(K,Q); raw v_exp_f32 + cvt_pk pack -> b64 writes into XOR-swizzled sP.
// __launch_bounds__(512, 4): VGPR cap 128 -- the (512,6) cap of 85 forced
// ~50 regs of scratch spill (R9: VGPR=40, 2.4 GB HBM scratch traffic, 3.9x
// slower). 2 blocks/CU (VGPR-limited; LDS 52224 B would allow 3).
// Schedule per tile (2 barriers): S+pack | F | issue K(t+1) | PV | E |
// issue V(t+1).
// ---------------------------------------------------------------------------
__global__ __launch_bounds__(512, 4) void flash_attn(
    const unsigned short* __restrict__ qkvb, const unsigned short* __restrict__ Vt,
    unsigned short* __restrict__ AO) {
  __shared__ __attribute__((aligned(16))) unsigned short sK[64 * 72];    //  9216 B
  __shared__ __attribute__((aligned(16))) unsigned short sVt[80 * 64];   // 10240 B
  __shared__ __attribute__((aligned(16))) unsigned short sP[256 * 64];   // 32768 B

  const int tid  = threadIdx.x;
  const int w    = tid >> 6;          // 0..7
  const int lane = tid & 63;
  const int quad = lane >> 4, l16 = lane & 15;
  const int s7   = l16 & 7;
  const int q0 = blockIdx.x * 256;
  const int h = blockIdx.y, b = blockIdx.z;

  const unsigned short* Qb = qkvb + ((size_t)(0 * BATCH + b) * HB + h) * NSEQ * DHD;
  const unsigned short* Kb = qkvb + ((size_t)(1 * BATCH + b) * HB + h) * NSEQ * DHD;
  const unsigned short* Vb = Vt + (size_t)(b * HB + h) * DHD * NSEQ;

  const short8 zs = {0, 0, 0, 0, 0, 0, 0, 0};
  const f32x4 zero = {0.f, 0.f, 0.f, 0.f};

  // staging source pointers; issue i = w + 8*j (9 x 1KB per array; wave 0
  // issues i=0 and i=8, waves 1..7 issue i=w).
  const int vswz = ((lane & 7) ^ (lane >> 3)) * 8;
  const unsigned short* pKn[2];
  const unsigned short* pVn[2];
#pragma unroll
  for (int j = 0; j < 2; j++) {
    int i = w + 8 * j;
    int ii = (i < 9) ? i : 0;
    pKn[j] = Kb + ii * 512 + lane * 8;
    pVn[j] = Vb + (size_t)(ii * 8 + (lane >> 3)) * NSEQ + vswz;
  }

  // prologue: issue K(0) -> sK and V(0) -> sVt
#pragma unroll
  for (int j = 0; j < 2; j++) {
    int i = w + 8 * j;
    if (i < 9) {
      gload_lds16(pKn[j], sK + i * 512);
      gload_lds16(pVn[j], sVt + i * 512);
      pKn[j] += 64 * 72;
      pVn[j] += 64;
    }
  }

  // ones row (d=72) and zero rows (73..79) of V; staging never touches them
  {
    int e = tid;   // 512 threads cover 512 entries exactly
    sVt[72 * 64 + e] = (e < 64) ? (unsigned short)0x3F80 : (unsigned short)0;
  }

  // Q fragments: 2 q-tiles per wave, rows q0 + w*32 + qt*16 + l16
  short8 aq[2][3];
#pragma unroll
  for (int qt = 0; qt < 2; qt++) {
    const unsigned short* qrow = Qb + (size_t)(q0 + w * 32 + qt * 16 + l16) * DHD;
    aq[qt][0] = *(const short8*)(qrow + quad * 8);
    aq[qt][1] = *(const short8*)(qrow + 32 + quad * 8);
    aq[qt][2] = (quad == 0) ? *(const short8*)(qrow + 64) : zs;
  }

  f32x4 o[2][5];
#pragma unroll
  for (int qt = 0; qt < 2; qt++)
#pragma unroll
    for (int nb = 0; nb < 5; nb++) o[qt][nb] = zero;

  // S-phase + pack (both q-tiles; each K fragment read once). SWAPPED
  // operands: D = S^T (row=kv, col=q); lane packs 4 consecutive kv with
  // 2 cvt_pk -> one b64 write into swizzled sP rows qt*128 + w*16 + l16.
  auto sphase_pack = [&]() {
    f32x4 st[2][4];
    __builtin_amdgcn_s_setprio(1);
#pragma unroll
    for (int nk = 0; nk < 4; nk++) {
      const unsigned short* kr = sK + (nk * 16 + l16) * 72;
      short8 kf0 = *(const short8*)(kr + quad * 8);
      short8 kf1 = *(const short8*)(kr + 32 + quad * 8);
      short8 kf2 = *(const short8*)(kr + 64);  // uniform; bogus k-slots masked by aq[2]=0
      f32x4 s0 = zero, s1 = zero;
      s0 = __builtin_amdgcn_mfma_f32_16x16x32_bf16(kf0, aq[0][0], s0, 0, 0, 0);
      s1 = __builtin_amdgcn_mfma_f32_16x16x32_bf16(kf0, aq[1][0], s1, 0, 0, 0);
      s0 = __builtin_amdgcn_mfma_f32_16x16x32_bf16(kf1, aq[0][1], s0, 0, 0, 0);
      s1 = __builtin_amdgcn_mfma_f32_16x16x32_bf16(kf1, aq[1][1], s1, 0, 0, 0);
      s0 = __builtin_amdgcn_mfma_f32_16x16x32_bf16(kf2, aq[0][2], s0, 0, 0, 0);
      s1 = __builtin_amdgcn_mfma_f32_16x16x32_bf16(kf2, aq[1][2], s1, 0, 0, 0);
      st[0][nk] = s0;
      st[1][nk] = s1;
    }
    __builtin_amdgcn_s_setprio(0);
#pragma unroll
    for (int qt = 0; qt < 2; qt++) {
      unsigned short* prow = sP + (qt * 128 + w * 16 + l16) * 64 + (quad & 1) * 4;
#pragma unroll
      for (int nk = 0; nk < 4; nk++) {
        int uoff = ((nk * 2 + (quad >> 1)) ^ s7) << 3;
        u32x2 pr;
        pr[0] = pkbf(exp2_raw(st[qt][nk][0]), exp2_raw(st[qt][nk][1]));
        pr[1] = pkbf(exp2_raw(st[qt][nk][2]), exp2_raw(st[qt][nk][3]));
        *(u32x2*)(prow + uoff) = pr;
      }
    }
  };

  // PV for the current tile: each V fragment read once, feeds both q-tiles.
  auto pv_phase = [&]() {
    __builtin_amdgcn_s_setprio(1);
#pragma unroll
    for (int kb = 0; kb < 2; kb++) {
      const unsigned short* pp =
          sP + (w * 16 + l16) * 64 + (((kb * 4 + quad) ^ s7) << 3);
      short8 pf0 = *(const short8*)pp;
      short8 pf1 = *(const short8*)(pp + 128 * 64);  // qt=1 rows (+128: same row&7)
#pragma unroll
      for (int nb = 0; nb < 5; nb++) {
        short8 vf = *(const short8*)(sVt + (nb * 16 + l16) * 64 +
                                     (((kb * 4 + quad) ^ s7) << 3));
        o[0][nb] = __builtin_amdgcn_mfma_f32_16x16x32_bf16(pf0, vf, o[0][nb], 0, 0, 0);
        o[1][nb] = __builtin_amdgcn_mfma_f32_16x16x32_bf16(pf1, vf, o[1][nb], 0, 0, 0);
      }
    }
    __builtin_amdgcn_s_setprio(0);
  };

  __syncthreads();   // drain K(0), V(0)

  for (int t = 0; t < 32; t++) {
    sphase_pack();           // S(t)+pack(t): reads sK, writes own sP rows

    __syncthreads();         // F: sK readers done; V(t) DMA drained (prev E)

    if (t < 31) {            // issue K(t+1) into sK (readers finished)
#pragma unroll
      for (int j = 0; j < 2; j++) {
        int i = w + 8 * j;
        if (i < 9) { gload_lds16(pKn[j], sK + i * 512); pKn[j] += 64 * 72; }
      }
    }

    pv_phase();              // PV(t): reads sVt=V(t), sP=P(t)

    __syncthreads();         // E: sVt readers done; K(t+1) DMA drained

    if (t < 31) {            // issue V(t+1); drains at next F
#pragma unroll
      for (int j = 0; j < 2; j++) {
        int i = w + 8 * j;
        if (i < 9) { gload_lds16(pVn[j], sVt + i * 512); pVn[j] += 64; }
      }
    }
  }

  // epilogue: l sits at dh=72 (nb=4, l16=8); broadcast within quad, normalize
#pragma unroll
  for (int qt = 0; qt < 2; qt++) {
    float inv[4];
#pragma unroll
    for (int r = 0; r < 4; r++)
      inv[r] = 1.0f / __shfl(o[qt][4][r], (quad << 4) + 8, 64);
    const int qrow = q0 + w * 32 + qt * 16 + quad * 4;
#pragma unroll
    for (int nb = 0; nb < 5; nb++) {
      int dh = nb * 16 + l16;
      if (dh < DHD) {
#pragma unroll
        for (int r = 0; r < 4; r++)
          AO[((size_t)b * NSEQ + qrow + r) * CDIM + h * DHD + dh] =
              f2bf(o[qt][nb][r] * inv[r]);
      }
    }
  }
}

// ---------------------------------------------------------------------------
extern "C" void kernel_launch(void* const* d_in, const int* in_sizes, int n_in,
                              void* d_out, int out_size, void* d_ws, size_t ws_size,
                              hipStream_t stream) {
  const float* x      = (const float*)d_in[0];
  const float* w_qkv  = (const float*)d_in[1];
  const float* w_proj = (const float*)d_in[2];
  const float* b_proj = (const float*)d_in[3];
  const float* qnw    = (const float*)d_in[4];
  const float* knw    = (const float*)d_in[5];
  float* out = (float*)d_out;

  char* ws = (char*)d_ws;
  // layout (bytes): xb 18.9M | wqkvb 8.0M | wprojb 2.7M | qkvb 37.7M | Vt 18.9M
  // AO aliases xb (xb dead after gemm1). Total 86.1 MB.
  unsigned short* xb    = (unsigned short*)(ws);
  unsigned short* wqkvb = (unsigned short*)(ws + 18874368);
  unsigned short* wprojb= (unsigned short*)(ws + 26836992);
  unsigned short* qkvb  = (unsigned short*)(ws + 29491200);
  unsigned short* Vt    = (unsigned short*)(ws + 67239936);
  unsigned short* AO    = xb;

  cvt_bf16<<<dim3((CVT_CHUNKS + 255) / 256), 256, 0, stream>>>(
      x, w_qkv, w_proj, xb, wqkvb, wprojb);
  gemm256_qkv<<<dim3(14, 32), 512, 0, stream>>>(xb, wqkvb, qkvb, Vt);
  rope_rms<<<dim3(NT), 256, 0, stream>>>(qkvb, qnw, knw);
  flash_attn<<<dim3(NSEQ / 256, HB, BATCH), 512, 0, stream>>>(qkvb, Vt, AO);
  gemm_bt<<<dim3(CDIM / 128, NT / 128), 256, 0, stream>>>(
      AO, wprojb, b_proj, out, NT, CDIM, CDIM);
}

// Round 11
// 317.130 us; speedup vs baseline: 2.3164x; 1.0191x over previous
//
#include <hip/hip_runtime.h>
#include <stdint.h>

// Problem constants
#define BATCH 4
#define NSEQ  2048
#define CDIM  1152
#define HB    16
#define DHD   72
#define D3    3456
#define NT    8192    // BATCH*NSEQ

typedef __attribute__((ext_vector_type(8))) short short8;       // 8 bf16 (4 VGPRs)
typedef __attribute__((ext_vector_type(8))) unsigned short u16x8;
typedef __attribute__((ext_vector_type(4))) unsigned short u16x4;
typedef __attribute__((ext_vector_type(2))) unsigned int u32x2;
typedef __attribute__((ext_vector_type(4))) float f32x4;

__device__ __forceinline__ float bf2f(unsigned short u) {
  return __uint_as_float(((unsigned)u) << 16);
}
__device__ __forceinline__ unsigned short f2bf(float f) {
  unsigned u = __float_as_uint(f);
  u += 0x7FFF + ((u >> 16) & 1);   // RNE
  return (unsigned short)(u >> 16);
}
// packed 2xf32 -> 2xbf16 (RNE) in one instruction (T12 recipe; no builtin)
__device__ __forceinline__ unsigned pkbf(float lo, float hi) {
  unsigned r;
  asm("v_cvt_pk_bf16_f32 %0, %1, %2" : "=v"(r) : "v"(lo), "v"(hi));
  return r;
}
// raw v_exp_f32: exact for |x| <= ~60 (our S is bounded by 12.3); avoids the
// ~7-instruction __ocml_exp2_f32 range-fixup expansion of exp2f.
__device__ __forceinline__ float exp2_raw(float x) {
  float r;
  asm("v_exp_f32 %0, %1" : "=v"(r) : "v"(x));
  return r;
}

// async 16B global->LDS copy: per-lane global addr, LDS dest = wave-uniform base + lane*16
__device__ __forceinline__ void gload_lds16(const unsigned short* g, unsigned short* l) {
  __builtin_amdgcn_global_load_lds(
      (const __attribute__((address_space(1))) void*)g,
      (__attribute__((address_space(3))) void*)l, 16, 0, 0);
}

// ---------------------------------------------------------------------------
// fp32 -> bf16 conversion prepass for x, w_qkv, w_proj (memory-bound).
// ---------------------------------------------------------------------------
#define XN    ((size_t)NT * CDIM)        // 9,437,184
#define WQN   ((size_t)D3 * CDIM)        // 3,981,312
#define WPN   ((size_t)CDIM * CDIM)      // 1,327,104
#define CVT_CHUNKS ((XN + WQN + WPN) / 4)  // 3,686,400 float4 chunks

__global__ __launch_bounds__(256) void cvt_bf16(
    const float* __restrict__ x, const float* __restrict__ wq,
    const float* __restrict__ wp, unsigned short* __restrict__ xb,
    unsigned short* __restrict__ wqb, unsigned short* __restrict__ wpb) {
  size_t c = (size_t)blockIdx.x * 256 + threadIdx.x;
  if (c >= CVT_CHUNKS) return;
  const float* src;
  unsigned short* dst;
  size_t e = c * 4;
  if (e < XN) { src = x + e; dst = xb + e; }
  else if (e < XN + WQN) { src = wq + (e - XN); dst = wqb + (e - XN); }
  else { src = wp + (e - XN - WQN); dst = wpb + (e - XN - WQN); }
  f32x4 v = *(const f32x4*)src;
  u16x4 r;
#pragma unroll
  for (int i = 0; i < 4; i++) r[i] = f2bf(v[i]);
  *(u16x4*)dst = r;
}

// ---------------------------------------------------------------------------
// GEMM-256: qkv = x * Wqkv^T, bf16 in, fp32 acc, bf16 scatter out.
// [UNCHANGED from R8]
// ---------------------------------------------------------------------------
__global__ __launch_bounds__(512, 2) void gemm256_qkv(
    const unsigned short* __restrict__ A, const unsigned short* __restrict__ Bt,
    unsigned short* __restrict__ qkvb, unsigned short* __restrict__ Vt) {
  __shared__ __attribute__((aligned(16))) unsigned short sA[2 * 256 * 64];  // 64 KB
  __shared__ __attribute__((aligned(16))) unsigned short sB[2 * 256 * 64];  // 64 KB

  const int K = CDIM;
  const int tid  = threadIdx.x;
  const int lane = tid & 63;
  const int w    = tid >> 6;          // 0..7
  const int wm   = w >> 2, wn = w & 3;
  const int quad = lane >> 4, l16 = lane & 15;
  const int s7l  = l16 & 7;

  const int lb  = blockIdx.y * gridDim.x + blockIdx.x;   // gridDim.x = 14
  const int xcd = lb & 7;
  const int pos = lb >> 3;            // 0..55
  const int m0 = (xcd * 4 + (pos & 3)) * 256;
  const int n0 = (pos >> 2) * 256;    // 0..13 tiles (tile 13 partial)

  const int r8 = lane >> 3;
  const int cu = (lane & 7) ^ r8;
  const unsigned short* gA = A  + (size_t)(m0 + w * 8 + r8) * K + cu * 8;
  const unsigned short* gB = Bt + (size_t)(n0 + w * 8 + r8) * K + cu * 8;

  const f32x4 zero = {0.f, 0.f, 0.f, 0.f};
  f32x4 acc[8][4];
#pragma unroll
  for (int i = 0; i < 8; i++)
#pragma unroll
    for (int j = 0; j < 4; j++) acc[i][j] = zero;

#pragma unroll
  for (int g = 0; g < 4; g++) {
    gload_lds16(gA + (size_t)g * 64 * K, sA + g * 4096 + w * 512);
    gload_lds16(gB + (size_t)g * 64 * K, sB + g * 4096 + w * 512);
  }
  __syncthreads();

  for (int t = 0; t < 18; t++) {
    const unsigned short* A_ = sA + (t & 1) * 16384;
    const unsigned short* B_ = sB + (t & 1) * 16384;
    unsigned short* An = sA + ((t + 1) & 1) * 16384;
    unsigned short* Bn = sB + ((t + 1) & 1) * 16384;
    const int ktn = (t + 1) * 64;

#pragma unroll
    for (int kk = 0; kk < 2; kk++) {
      short8 a[8], b[4];
#pragma unroll
      for (int i = 0; i < 8; i++)
        a[i] = *(const short8*)(A_ + (wm * 128 + i * 16 + l16) * 64 +
                                (((kk * 4 + quad) ^ s7l) << 3));
#pragma unroll
      for (int j = 0; j < 4; j++)
        b[j] = *(const short8*)(B_ + (wn * 64 + j * 16 + l16) * 64 +
                                (((kk * 4 + quad) ^ s7l) << 3));

      if (t < 17) {
#pragma unroll
        for (int g = 0; g < 4; g++) {
          if (kk == 0)
            gload_lds16(gA + (size_t)g * 64 * K + ktn, An + g * 4096 + w * 512);
          else
            gload_lds16(gB + (size_t)g * 64 * K + ktn, Bn + g * 4096 + w * 512);
        }
      }

      __builtin_amdgcn_s_setprio(1);
#pragma unroll
      for (int i = 0; i < 8; i++)
#pragma unroll
        for (int j = 0; j < 4; j++)
          acc[i][j] = __builtin_amdgcn_mfma_f32_16x16x32_bf16(a[i], b[j], acc[i][j], 0, 0, 0);
      __builtin_amdgcn_s_setprio(0);
    }
    __syncthreads();
  }

#pragma unroll
  for (int i = 0; i < 8; i++) {
    int row = m0 + wm * 128 + i * 16 + quad * 4;
    int b_ = row >> 11;
    int n  = row & 2047;
#pragma unroll
    for (int j = 0; j < 4; j++) {
      int col = n0 + wn * 64 + j * 16 + l16;
      if (col < D3) {
        int s  = col / CDIM;
        int rm = col - s * CDIM;
        int h  = rm / DHD;
        int dh = rm - h * DHD;
        if (s == 2) {
#pragma unroll
          for (int r = 0; r < 4; r++)
            Vt[((size_t)(b_ * HB + h) * DHD + dh) * NSEQ + n + r] = f2bf(acc[i][j][r]);
        } else {
#pragma unroll
          for (int r = 0; r < 4; r++)
            qkvb[(((size_t)(s * BATCH + b_) * HB + h) * NSEQ + (n + r)) * DHD + dh] =
                f2bf(acc[i][j][r]);
        }
      }
    }
  }
}

// ---------------------------------------------------------------------------
// GEMM-BT (bf16 in): output projection. [UNCHANGED from R8]
// ---------------------------------------------------------------------------
__global__ __launch_bounds__(256) void gemm_bt(
    const unsigned short* __restrict__ A, const unsigned short* __restrict__ Bt,
    const float* __restrict__ bias, float* __restrict__ Cout, int M, int Dn, int K) {
  __shared__ __attribute__((aligned(16))) unsigned short sA[128 * 64];  // 16 KB
  __shared__ __attribute__((aligned(16))) unsigned short sB[128 * 64];  // 16 KB

  const int tid  = threadIdx.x;
  const int lane = tid & 63;
  const int w    = tid >> 6;
  const int wm   = w >> 1, wn = w & 1;
  const int quad = lane >> 4, l16 = lane & 15;
  const int s7l  = l16 & 7;

  const int gx  = gridDim.x;
  const int lb  = blockIdx.y * gx + blockIdx.x;
  const int xcd = lb & 7;
  const int pos = lb >> 3;
  const int m0 = ((xcd << 3) + (pos & 7)) * 128;
  const int n0 = (pos >> 3) * 128;

  const int r8 = lane >> 3;
  const int cu = (lane & 7) ^ r8;
  const unsigned short* gA = A  + (size_t)(m0 + w * 32 + r8) * K + cu * 8;
  const unsigned short* gB = Bt + (size_t)(n0 + w * 32 + r8) * K + cu * 8;

  const f32x4 zero = {0.f, 0.f, 0.f, 0.f};
  f32x4 acc[4][4];
#pragma unroll
  for (int i = 0; i < 4; i++)
#pragma unroll
    for (int j = 0; j < 4; j++) acc[i][j] = zero;

  for (int kt = 0; kt < K; kt += 64) {
#pragma unroll
    for (int i = 0; i < 4; i++) {
      gload_lds16(gA + (size_t)i * 8 * K + kt, sA + (w * 4 + i) * 512);
      gload_lds16(gB + (size_t)i * 8 * K + kt, sB + (w * 4 + i) * 512);
    }
    __syncthreads();

#pragma unroll
    for (int kk = 0; kk < 2; kk++) {
      short8 a[4], b[4];
#pragma unroll
      for (int i = 0; i < 4; i++) {
        a[i] = *(const short8*)(sA + (wm * 64 + i * 16 + l16) * 64 +
                                (((kk * 4 + quad) ^ s7l) << 3));
        b[i] = *(const short8*)(sB + (wn * 64 + i * 16 + l16) * 64 +
                                (((kk * 4 + quad) ^ s7l) << 3));
      }
#pragma unroll
      for (int i = 0; i < 4; i++)
#pragma unroll
        for (int j = 0; j < 4; j++)
          acc[i][j] = __builtin_amdgcn_mfma_f32_16x16x32_bf16(a[i], b[j], acc[i][j], 0, 0, 0);
    }
    __syncthreads();
  }

#pragma unroll
  for (int i = 0; i < 4; i++) {
    int row = m0 + wm * 64 + i * 16 + quad * 4;
#pragma unroll
    for (int j = 0; j < 4; j++) {
      int col = n0 + wn * 64 + j * 16 + l16;
      float bb = bias ? bias[col] : 0.f;
#pragma unroll
      for (int r = 0; r < 4; r++)
        Cout[(size_t)(row + r) * Dn + col] = acc[i][j][r] + bb;
    }
  }
}

// ---------------------------------------------------------------------------
// RoPE + RMSNorm. [UNCHANGED from R8]
// ---------------------------------------------------------------------------
__global__ __launch_bounds__(256) void rope_rms(
    unsigned short* __restrict__ qkvb,
    const float* __restrict__ qw, const float* __restrict__ kw) {
  const int blk = blockIdx.x;
  const int b = blk >> 11;
  const int n = blk & 2047;
  const int tid = threadIdx.x;

  __shared__ float sv[2][CDIM];   // 9216 B
  __shared__ float srsq[2][HB];

  const float nf = (float)n;
  const float l2t_over_half = 13.287712379549449f / 36.0f;  // log2(10000)/36
  const float scale2 = 0.17002329230297715f;                // 72^-0.5 * log2(e)

  for (int g = tid; g < 288; g += 256) {
    int sel = (g >= 144) ? 1 : 0;
    int gg  = g - sel * 144;
    int h   = gg / 9;
    int u   = gg - h * 9;
    const unsigned short* src =
        qkvb + (((size_t)(sel * BATCH + b) * HB + h) * NSEQ + n) * DHD + u * 8;
    u16x8 v = *(const u16x8*)src;
    float* dst = &sv[sel][h * DHD + u * 8];
#pragma unroll
    for (int r = 0; r < 8; r++) dst[r] = bf2f(v[r]);
  }
  __syncthreads();

  for (int p = tid; p < 1152; p += 256) {
    int sel = (p >= 576) ? 1 : 0;
    int pp  = p - sel * 576;
    int h   = pp / 36;
    int i   = pp - h * 36;
    float* row = &sv[sel][h * DHD];
    float x1 = row[i], x2 = row[i + 36];
    float ang = nf * exp2f(-l2t_over_half * (float)i);
    float sn, cs;
    __sincosf(ang, &sn, &cs);
    row[i]      = x1 * cs - x2 * sn;
    row[i + 36] = x2 * cs + x1 * sn;
  }
  __syncthreads();

  if (tid < 128) {
    int sel = tid >> 6;
    int h = (tid & 63) >> 2, p = tid & 3;
    float s = 0.f;
#pragma unroll
    for (int d = 0; d < 18; d++) {
      float v = sv[sel][h * DHD + p * 18 + d];
      s += v * v;
    }
    s += __shfl_xor(s, 1);
    s += __shfl_xor(s, 2);
    if (p == 0)
      srsq[sel][h] = rsqrtf(s * (1.0f / 72.0f) + 1e-6f) * (sel ? 1.0f : scale2);
  }
  __syncthreads();

  for (int g = tid; g < 288; g += 256) {
    int sel = (g >= 144) ? 1 : 0;
    int gg  = g - sel * 144;
    int h   = gg / 9;
    int u   = gg - h * 9;
    float rs = srsq[sel][h];
    const float* wn = (sel ? kw : qw) + u * 8;
    const float* s = &sv[sel][h * DHD + u * 8];
    u16x8 o;
#pragma unroll
    for (int r = 0; r < 8; r++) o[r] = f2bf(s[r] * rs * wn[r]);
    unsigned short* dst =
        qkvb + (((size_t)(sel * BATCH + b) * HB + h) * NSEQ + n) * DHD + u * 8;
    *(u16x8*)dst = o;
  }
}

// ---------------------------------------------------------------------------
// Flash attention, no-max softmax. QBLK=256: 512 thr = 8 waves, each owning
// 32 q-rows (2 fused q-tiles of 16). KV tiles of 64. S^T via swapped
// mfma(K,Q); raw v_exp_f32 + cvt_pk pack -> b64 writes into XOR-swizzled sP.
// SINGLE barrier per tile: sP is wave-local (wave w writes and reads only
// rows {qt*128 + w*16 .. +16}; same-wave DS ops are in-order), so the only
// cross-wave hazards are sK/sVt. With BOTH K and V double-buffered, tile t:
//   issue K(t+1),V(t+1) -> buf^1 ; S(t)+pack ; PV(t) ; barrier
// (barrier's vmcnt(0) drains the DMAs issued a full tile earlier; buffer
// buf^1's last readers finished before the PREVIOUS barrier). 33 barriers
// vs 64. LDS 71680 B -> 2 blocks/CU (VGPR 64, launch_bounds(512,4) -- the
// (512,6) cap of 85 caused a 50-reg spill, R9: 3.9x slower).
// ---------------------------------------------------------------------------
__global__ __launch_bounds__(512, 4) void flash_attn(
    const unsigned short* __restrict__ qkvb, const unsigned short* __restrict__ Vt,
    unsigned short* __restrict__ AO) {
  __shared__ __attribute__((aligned(16))) unsigned short sK[2 * 64 * 72];   // 18432 B
  __shared__ __attribute__((aligned(16))) unsigned short sVt[2 * 80 * 64];  // 20480 B
  __shared__ __attribute__((aligned(16))) unsigned short sP[256 * 64];      // 32768 B

  const int tid  = threadIdx.x;
  const int w    = tid >> 6;          // 0..7
  const int lane = tid & 63;
  const int quad = lane >> 4, l16 = lane & 15;
  const int s7   = l16 & 7;
  const int q0 = blockIdx.x * 256;
  const int h = blockIdx.y, b = blockIdx.z;

  const unsigned short* Qb = qkvb + ((size_t)(0 * BATCH + b) * HB + h) * NSEQ * DHD;
  const unsigned short* Kb = qkvb + ((size_t)(1 * BATCH + b) * HB + h) * NSEQ * DHD;
  const unsigned short* Vb = Vt + (size_t)(b * HB + h) * DHD * NSEQ;

  const short8 zs = {0, 0, 0, 0, 0, 0, 0, 0};
  const f32x4 zero = {0.f, 0.f, 0.f, 0.f};

  // staging source pointers; issue i = w + 8*j (9 x 1KB per array; wave 0
  // issues i=0 and i=8, waves 1..7 issue i=w).
  const int vswz = ((lane & 7) ^ (lane >> 3)) * 8;
  const unsigned short* pKn[2];
  const unsigned short* pVn[2];
#pragma unroll
  for (int j = 0; j < 2; j++) {
    int i = w + 8 * j;
    int ii = (i < 9) ? i : 0;
    pKn[j] = Kb + ii * 512 + lane * 8;
    pVn[j] = Vb + (size_t)(ii * 8 + (lane >> 3)) * NSEQ + vswz;
  }

  // prologue: issue K(0) -> sK buf0 and V(0) -> sVt buf0
#pragma unroll
  for (int j = 0; j < 2; j++) {
    int i = w + 8 * j;
    if (i < 9) {
      gload_lds16(pKn[j], sK + i * 512);
      gload_lds16(pVn[j], sVt + i * 512);
      pKn[j] += 64 * 72;
      pVn[j] += 64;
    }
  }

  // ones row (d=72) and zero rows (73..79) of V in BOTH buffers; staging
  // never touches rows 72..79.
  {
    int e = tid;   // 512 threads cover 512 entries exactly
    unsigned short v = (e < 64) ? (unsigned short)0x3F80 : (unsigned short)0;
    sVt[72 * 64 + e] = v;
    sVt[80 * 64 + 72 * 64 + e] = v;
  }

  // Q fragments: 2 q-tiles per wave, rows q0 + w*32 + qt*16 + l16
  short8 aq[2][3];
#pragma unroll
  for (int qt = 0; qt < 2; qt++) {
    const unsigned short* qrow = Qb + (size_t)(q0 + w * 32 + qt * 16 + l16) * DHD;
    aq[qt][0] = *(const short8*)(qrow + quad * 8);
    aq[qt][1] = *(const short8*)(qrow + 32 + quad * 8);
    aq[qt][2] = (quad == 0) ? *(const short8*)(qrow + 64) : zs;
  }

  f32x4 o[2][5];
#pragma unroll
  for (int qt = 0; qt < 2; qt++)
#pragma unroll
    for (int nb = 0; nb < 5; nb++) o[qt][nb] = zero;

  // S-phase + pack (both q-tiles; each K fragment read once). SWAPPED
  // operands: D = S^T (row=kv, col=q); lane packs 4 consecutive kv with
  // 2 cvt_pk -> one b64 write into swizzled sP rows qt*128 + w*16 + l16.
  auto sphase_pack = [&](const unsigned short* sKb) {
    f32x4 st[2][4];
    __builtin_amdgcn_s_setprio(1);
#pragma unroll
    for (int nk = 0; nk < 4; nk++) {
      const unsigned short* kr = sKb + (nk * 16 + l16) * 72;
      short8 kf0 = *(const short8*)(kr + quad * 8);
      short8 kf1 = *(const short8*)(kr + 32 + quad * 8);
      short8 kf2 = *(const short8*)(kr + 64);  // uniform; bogus k-slots masked by aq[2]=0
      f32x4 s0 = zero, s1 = zero;
      s0 = __builtin_amdgcn_mfma_f32_16x16x32_bf16(kf0, aq[0][0], s0, 0, 0, 0);
      s1 = __builtin_amdgcn_mfma_f32_16x16x32_bf16(kf0, aq[1][0], s1, 0, 0, 0);
      s0 = __builtin_amdgcn_mfma_f32_16x16x32_bf16(kf1, aq[0][1], s0, 0, 0, 0);
      s1 = __builtin_amdgcn_mfma_f32_16x16x32_bf16(kf1, aq[1][1], s1, 0, 0, 0);
      s0 = __builtin_amdgcn_mfma_f32_16x16x32_bf16(kf2, aq[0][2], s0, 0, 0, 0);
      s1 = __builtin_amdgcn_mfma_f32_16x16x32_bf16(kf2, aq[1][2], s1, 0, 0, 0);
      st[0][nk] = s0;
      st[1][nk] = s1;
    }
    __builtin_amdgcn_s_setprio(0);
#pragma unroll
    for (int qt = 0; qt < 2; qt++) {
      unsigned short* prow = sP + (qt * 128 + w * 16 + l16) * 64 + (quad & 1) * 4;
#pragma unroll
      for (int nk = 0; nk < 4; nk++) {
        int uoff = ((nk * 2 + (quad >> 1)) ^ s7) << 3;
        u32x2 pr;
        pr[0] = pkbf(exp2_raw(st[qt][nk][0]), exp2_raw(st[qt][nk][1]));
        pr[1] = pkbf(exp2_raw(st[qt][nk][2]), exp2_raw(st[qt][nk][3]));
        *(u32x2*)(prow + uoff) = pr;
      }
    }
  };

  // PV for the current tile: each V fragment read once, feeds both q-tiles.
  // Reads the wave's OWN sP rows (written by sphase_pack above; same-wave
  // DS ordering makes this barrier-free).
  auto pv_phase = [&](const unsigned short* sVb) {
    __builtin_amdgcn_s_setprio(1);
#pragma unroll
    for (int kb = 0; kb < 2; kb++) {
      const unsigned short* pp =
          sP + (w * 16 + l16) * 64 + (((kb * 4 + quad) ^ s7) << 3);
      short8 pf0 = *(const short8*)pp;
      short8 pf1 = *(const short8*)(pp + 128 * 64);  // qt=1 rows (+128: same row&7)
#pragma unroll
      for (int nb = 0; nb < 5; nb++) {
        short8 vf = *(const short8*)(sVb + (nb * 16 + l16) * 64 +
                                     (((kb * 4 + quad) ^ s7) << 3));
        o[0][nb] = __builtin_amdgcn_mfma_f32_16x16x32_bf16(pf0, vf, o[0][nb], 0, 0, 0);
        o[1][nb] = __builtin_amdgcn_mfma_f32_16x16x32_bf16(pf1, vf, o[1][nb], 0, 0, 0);
      }
    }
    __builtin_amdgcn_s_setprio(0);
  };

  __syncthreads();   // drain K(0), V(0)

  for (int t = 0; t < 32; t++) {
    const unsigned short* sKb = sK + (t & 1) * (64 * 72);
    const unsigned short* sVb = sVt + (t & 1) * (80 * 64);

    if (t < 31) {    // issue K(t+1), V(t+1) -> other buffer (its readers
                     // finished before the PREVIOUS barrier)
      unsigned short* dK = sK + ((t + 1) & 1) * (64 * 72);
      unsigned short* dV = sVt + ((t + 1) & 1) * (80 * 64);
#pragma unroll
      for (int j = 0; j < 2; j++) {
        int i = w + 8 * j;
        if (i < 9) {
          gload_lds16(pKn[j], dK + i * 512);
          gload_lds16(pVn[j], dV + i * 512);
          pKn[j] += 64 * 72;
          pVn[j] += 64;
        }
      }
    }

    sphase_pack(sKb);        // S(t)+pack(t): reads sK[t&1], writes own sP rows
    pv_phase(sVb);           // PV(t): reads sVt[t&1] + own sP rows

    __syncthreads();         // drains K/V(t+1) DMA; releases buf[t&1] for t+2
  }

  // epilogue: l sits at dh=72 (nb=4, l16=8); broadcast within quad, normalize
#pragma unroll
  for (int qt = 0; qt < 2; qt++) {
    float inv[4];
#pragma unroll
    for (int r = 0; r < 4; r++)
      inv[r] = 1.0f / __shfl(o[qt][4][r], (quad << 4) + 8, 64);
    const int qrow = q0 + w * 32 + qt * 16 + quad * 4;
#pragma unroll
    for (int nb = 0; nb < 5; nb++) {
      int dh = nb * 16 + l16;
      if (dh < DHD) {
#pragma unroll
        for (int r = 0; r < 4; r++)
          AO[((size_t)b * NSEQ + qrow + r) * CDIM + h * DHD + dh] =
              f2bf(o[qt][nb][r] * inv[r]);
      }
    }
  }
}

// ---------------------------------------------------------------------------
extern "C" void kernel_launch(void* const* d_in, const int* in_sizes, int n_in,
                              void* d_out, int out_size, void* d_ws, size_t ws_size,
                              hipStream_t stream) {
  const float* x      = (const float*)d_in[0];
  const float* w_qkv  = (const float*)d_in[1];
  const float* w_proj = (const float*)d_in[2];
  const float* b_proj = (const float*)d_in[3];
  const float* qnw    = (const float*)d_in[4];
  const float* knw    = (const float*)d_in[5];
  float* out = (float*)d_out;

  char* ws = (char*)d_ws;
  // layout (bytes): xb 18.9M | wqkvb 8.0M | wprojb 2.7M | qkvb 37.7M | Vt 18.9M
  // AO aliases xb (xb dead after gemm1). Total 86.1 MB.
  unsigned short* xb    = (unsigned short*)(ws);
  unsigned short* wqkvb = (unsigned short*)(ws + 18874368);
  unsigned short* wprojb= (unsigned short*)(ws + 26836992);
  unsigned short* qkvb  = (unsigned short*)(ws + 29491200);
  unsigned short* Vt    = (unsigned short*)(ws + 67239936);
  unsigned short* AO    = xb;

  cvt_bf16<<<dim3((CVT_CHUNKS + 255) / 256), 256, 0, stream>>>(
      x, w_qkv, w_proj, xb, wqkvb, wprojb);
  gemm256_qkv<<<dim3(14, 32), 512, 0, stream>>>(xb, wqkvb, qkvb, Vt);
  rope_rms<<<dim3(NT), 256, 0, stream>>>(qkvb, qnw, knw);
  flash_attn<<<dim3(NSEQ / 256, HB, BATCH), 512, 0, stream>>>(qkvb, Vt, AO);
  gemm_bt<<<dim3(CDIM / 128, NT / 128), 256, 0, stream>>>(
      AO, wprojb, b_proj, out, NT, CDIM, CDIM);
}